// Round 8
// baseline (249.494 us; speedup 1.0000x reference)
//
#include <hip/hip_runtime.h>

// ---------------------------------------------------------------------------
// MultiHeadCausalAttention: B=2, T=4096, C=768, H=12, Dh=64
// v14: attn rebuilt for LDS-bandwidth (the measured binding constraint:
//      96KB LDS traffic per 128qx64k block-iter vs 520cyc MFMA; ~1100-1500cyc
//      of a ~1840cyc iteration). New shape: 128-thread blocks (2 waves), each
//      wave holds 4 q-frags (64 q-rows) -> K/V frags read once per wave serve
//      4 q-frags; only 2 waves duplicate them. LDS/work x0.67. Per-qf fused
//      QK->pack->PV lets sPT shrink to 2 rotating bufs/wave: LDS 40KB ->
//      4 blocks/CU (8 waves/CU). Grid/pairing/combine identical to v13
//      (768 blocks = exactly 3/CU, balanced 33/33 k-split). All reg indexing
//      static (v9 spill lesson); launch_bounds(128,2) caps VGPR<=256.
//      gemm_qkv/gemm_out keep v13's XCD swizzles.
// ---------------------------------------------------------------------------

#define NHEADS 12
#define DHEAD  64
#define TSEQ   4096
#define BATCH  2
#define CMODEL 768
#define MTOT   (BATCH * TSEQ)   /* 8192 */
#define NQKV   (3 * CMODEL)     /* 2304 */
#define NBH    (BATCH * NHEADS) /* 24 */

typedef __attribute__((ext_vector_type(8))) short s16x8;
typedef __attribute__((ext_vector_type(4))) float f32x4;
typedef __attribute__((ext_vector_type(4))) unsigned short u16x4;
typedef __attribute__((ext_vector_type(2))) unsigned int u32x2;

__device__ __forceinline__ unsigned short f2bf(float f) {
    unsigned u = __builtin_bit_cast(unsigned, f);
    u += 0x7fffu + ((u >> 16) & 1u);   // round-to-nearest-even
    return (unsigned short)(u >> 16);
}

__device__ __forceinline__ unsigned pk2bf(float a, float b) {
    return (unsigned)f2bf(a) | ((unsigned)f2bf(b) << 16);
}

// packed f32x2 -> bf16x2 in one VOP3 (no builtin on gfx950; RTNE; S0->lo)
__device__ __forceinline__ unsigned cvtpk(float lo, float hi) {
    unsigned r;
    asm("v_cvt_pk_bf16_f32 %0, %1, %2" : "=v"(r) : "v"(lo), "v"(hi));
    return r;
}

__device__ __forceinline__ float fexp2(float x) {
    return __builtin_amdgcn_exp2f(x);
}

// async global -> LDS, 16B per lane; lds dest = wave-uniform base + lane*16.
__device__ __forceinline__ void async_load16(const void* g, void* l) {
    __builtin_amdgcn_global_load_lds(
        (const __attribute__((address_space(1))) unsigned*)g,
        (__attribute__((address_space(3))) unsigned*)l, 16, 0, 0);
}

// raw workgroup barrier with backend-scheduler pinning (no vmcnt drain)
__device__ __forceinline__ void raw_barrier() {
    __builtin_amdgcn_sched_barrier(0);
    __builtin_amdgcn_s_barrier();
    __builtin_amdgcn_sched_barrier(0);
}

// --------------------------- fp32 -> bf16 cvt (3 tensors, 1 launch) --------
__global__ __launch_bounds__(256) void cvt3_kernel(
    const float* __restrict__ s0, const float* __restrict__ s1,
    const float* __restrict__ s2,
    unsigned short* __restrict__ d0, unsigned short* __restrict__ d1,
    unsigned short* __restrict__ d2, int n0, int n1, int n2)
{
    int i = blockIdx.x * 256 + threadIdx.x;
    const float* s; unsigned short* d; int j;
    if (i < n0)                { s = s0; d = d0; j = i; }
    else if (i < n0 + n1)      { s = s1; d = d1; j = i - n0; }
    else if (i < n0 + n1 + n2) { s = s2; d = d2; j = i - n0 - n1; }
    else return;
    f32x4 v = ((const f32x4*)s)[j];
    u32x2 o;
    o.x = pk2bf(v.x, v.y);
    o.y = pk2bf(v.z, v.w);
    ((u32x2*)d)[j] = o;
}

// --------------------------- QKV projection GEMM (128x128) -----------------
// XCD-chunked swizzle: 1152 blocks, 144/XCD = 8 m-panels x 18 n-blocks.
__global__ __launch_bounds__(256) void gemm_qkv_kernel(
    const unsigned short* __restrict__ A,    // [8192][768] bf16 (x)
    const unsigned short* __restrict__ Bw,   // [2304][768] bf16 (w_qkv)
    const float* __restrict__ bias,          // [2304]
    unsigned short* __restrict__ Qb,
    unsigned short* __restrict__ Kb,
    unsigned short* __restrict__ Vt)
{
    __shared__ unsigned short sA[128][64];
    __shared__ unsigned short sB[128][64];
    const int idx = blockIdx.x + blockIdx.y * 18;   // hw dispatch order
    const int lid = (idx & 7) * 144 + (idx >> 3);   // bijective (1152%8==0)
    const int n0 = (lid % 18) * 128;
    const int m0 = (lid / 18) * 128;
    const int tid = threadIdx.x;
    const int l = tid & 63, g = l >> 4, l15 = l & 15;
    const int w = tid >> 6, wm = w & 1, wn = w >> 1;
    const int wbase = tid & 192;
    const int seg = n0 / 768;                // 0=Q 1=K 2=V (block-uniform)

    f32x4 acc[4][4];
#pragma unroll
    for (int a = 0; a < 4; a++)
#pragma unroll
        for (int b = 0; b < 4; b++) acc[a][b] = (f32x4){0.f, 0.f, 0.f, 0.f};

    if (seg < 2) {
        // ---- Q/K path: acc[nt][mt] = C^T tile (rows = n, cols = m) ----
        for (int k0 = 0; k0 < 768; k0 += 64) {
#pragma unroll
            for (int i = 0; i < 4; i++) {
                const int idx2 = i * 256 + tid;
                const int row = idx2 >> 3, pc = idx2 & 7;
                const int lc = pc ^ (row & 7);
                async_load16(&A[(size_t)(m0 + row) * 768 + k0 + lc * 8],
                             &sA[0][0] + (size_t)(i * 256 + wbase) * 8);
                async_load16(&Bw[(size_t)(n0 + row) * 768 + k0 + lc * 8],
                             &sB[0][0] + (size_t)(i * 256 + wbase) * 8);
            }
            __syncthreads();
#pragma unroll
            for (int ks = 0; ks < 2; ks++) {
                const int cc = ((ks * 4 + g) ^ (l15 & 7)) * 8;
                s16x8 af[4], bf[4];
#pragma unroll
                for (int mt = 0; mt < 4; mt++)
                    af[mt] = *(const s16x8*)&sA[wm * 64 + mt * 16 + l15][cc];
#pragma unroll
                for (int nt = 0; nt < 4; nt++)
                    bf[nt] = *(const s16x8*)&sB[wn * 64 + nt * 16 + l15][cc];
#pragma unroll
                for (int nt = 0; nt < 4; nt++)
#pragma unroll
                    for (int mt = 0; mt < 4; mt++)
                        acc[nt][mt] = __builtin_amdgcn_mfma_f32_16x16x32_bf16(
                            bf[nt], af[mt], acc[nt][mt], 0, 0, 0);
            }
            __syncthreads();
        }

        unsigned short* dst = (seg == 0) ? Qb : Kb;
        const float sc = (seg == 0) ? 0.18033688011f : 1.0f;  // 0.125*log2e
        const int hh = ((n0 - seg * 768) + wn * 64) >> 6;     // uniform head
#pragma unroll
        for (int nt = 0; nt < 4; nt++) {
            const int dh = nt * 16 + g * 4;                    // + r
            const f32x4 bv4 = *(const f32x4*)&bias[n0 + wn * 64 + dh];
#pragma unroll
            for (int mt = 0; mt < 4; mt++) {
                const int m = m0 + wm * 64 + mt * 16 + l15;
                const int b = m >> 12, t = m & 4095;
                u32x2 pk;
                pk.x = pk2bf((acc[nt][mt][0] + bv4[0]) * sc,
                             (acc[nt][mt][1] + bv4[1]) * sc);
                pk.y = pk2bf((acc[nt][mt][2] + bv4[2]) * sc,
                             (acc[nt][mt][3] + bv4[3]) * sc);
                *(u32x2*)&dst[(((size_t)(b * NHEADS + hh) * TSEQ + t) << 6) + dh] = pk;
            }
        }
    } else {
        // ---- V path: acc[mt][nt] = C tile (rows = m), store transposed ----
        for (int k0 = 0; k0 < 768; k0 += 64) {
#pragma unroll
            for (int i = 0; i < 4; i++) {
                const int idx2 = i * 256 + tid;
                const int row = idx2 >> 3, pc = idx2 & 7;
                const int lc = pc ^ (row & 7);
                async_load16(&A[(size_t)(m0 + row) * 768 + k0 + lc * 8],
                             &sA[0][0] + (size_t)(i * 256 + wbase) * 8);
                async_load16(&Bw[(size_t)(n0 + row) * 768 + k0 + lc * 8],
                             &sB[0][0] + (size_t)(i * 256 + wbase) * 8);
            }
            __syncthreads();
#pragma unroll
            for (int ks = 0; ks < 2; ks++) {
                const int cc = ((ks * 4 + g) ^ (l15 & 7)) * 8;
                s16x8 af[4], bf[4];
#pragma unroll
                for (int mt = 0; mt < 4; mt++)
                    af[mt] = *(const s16x8*)&sA[wm * 64 + mt * 16 + l15][cc];
#pragma unroll
                for (int nt = 0; nt < 4; nt++)
                    bf[nt] = *(const s16x8*)&sB[wn * 64 + nt * 16 + l15][cc];
#pragma unroll
                for (int mt = 0; mt < 4; mt++)
#pragma unroll
                    for (int nt = 0; nt < 4; nt++)
                        acc[mt][nt] = __builtin_amdgcn_mfma_f32_16x16x32_bf16(
                            af[mt], bf[nt], acc[mt][nt], 0, 0, 0);
            }
            __syncthreads();
        }

#pragma unroll
        for (int nt = 0; nt < 4; nt++) {
            const int n = n0 + wn * 64 + nt * 16 + l15;
            const float bv = bias[n];
            const int hh = (n - 1536) >> 6;
            const int dh = n & 63;
#pragma unroll
            for (int mt = 0; mt < 4; mt++) {
                const int mg = m0 + wm * 64 + mt * 16 + g * 4;
                const int b = mg >> 12, t = mg & 4095;
                u32x2 pk;
                pk.x = pk2bf(acc[mt][nt][0] + bv, acc[mt][nt][1] + bv);
                pk.y = pk2bf(acc[mt][nt][2] + bv, acc[mt][nt][3] + bv);
                *(u32x2*)&Vt[((size_t)(b * NHEADS + hh) * DHEAD + dh) * TSEQ + t] = pk;
            }
        }
    }
}

// --------------------------- flash attention v14 ---------------------------
// Per-iteration body: 4 q-frags per wave. K/V frags read ONCE per wave and
// reused across all 4 q-frags (the LDS-BW lever). Per-qf fused QK->pack->PV
// with 2 rotating sPT buffers (WAR distance 2). Single call site per loop.
__device__ __forceinline__ void process_tile4(
    const unsigned short (&sKb)[64][64],
    const unsigned short (&sVb)[64][64],
    unsigned short (&sPTw)[2][16][64],   // [qf&1][16][64]
    const s16x8 (&qa)[4][2],             // [qf][ks]
    f32x4 (&o)[4][4], f32x4 (&lac)[4],
    s16x8 vones, int kt, int qg0, bool mask, int g, int l15)
{
    const int xk = l15 & 7;

    // ---- K and V fragments: one read each, reused by 4 q-frags ----
    s16x8 ak[2][4], av[2][4];
#pragma unroll
    for (int ks = 0; ks < 2; ks++) {
        const int cc = ((ks * 4 + g) ^ xk) * 8;
#pragma unroll
        for (int nt = 0; nt < 4; nt++) {
            ak[ks][nt] = *(const s16x8*)&sKb[nt * 16 + l15][cc];
            av[ks][nt] = *(const s16x8*)&sVb[nt * 16 + l15][cc];
        }
    }

#pragma unroll
    for (int qf = 0; qf < 4; qf++) {
        // ---- QK^T for this q-frag ----
        f32x4 st[4];
#pragma unroll
        for (int nt = 0; nt < 4; nt++) st[nt] = (f32x4){0.f, 0.f, 0.f, 0.f};
        __builtin_amdgcn_s_setprio(1);
#pragma unroll
        for (int ks = 0; ks < 2; ks++)
#pragma unroll
            for (int nt = 0; nt < 4; nt++)
                st[nt] = __builtin_amdgcn_mfma_f32_16x16x32_bf16(
                    ak[ks][nt], qa[qf][ks], st[nt], 0, 0, 0);
        __builtin_amdgcn_s_setprio(0);

        // ---- causal mask (block-uniform predicate) ----
        if (mask) {
            const int qg = qg0 + qf * 16;
#pragma unroll
            for (int nt = 0; nt < 4; nt++)
#pragma unroll
                for (int r = 0; r < 4; r++)
                    if (kt + nt * 16 + g * 4 + r > qg) st[nt][r] = -1e30f;
        }

        // ---- softmax numerator + pack (wave-private, no barrier) ----
#pragma unroll
        for (int nt = 0; nt < 4; nt++) {
            float p0 = fexp2(st[nt][0]);
            float p1 = fexp2(st[nt][1]);
            float p2 = fexp2(st[nt][2]);
            float p3 = fexp2(st[nt][3]);
            u32x2 pk;
            pk.x = cvtpk(p0, p1);
            pk.y = cvtpk(p2, p3);
            const int phys = ((nt * 2 + (g >> 1)) ^ xk) * 8 + (g & 1) * 4;
            *(u32x2*)&sPTw[qf & 1][l15][phys] = pk;
        }

        // ---- PV for this q-frag + l via ones-row MFMA ----
        __builtin_amdgcn_s_setprio(1);
#pragma unroll
        for (int ks = 0; ks < 2; ks++) {
            const int cc = ((ks * 4 + g) ^ xk) * 8;
            const s16x8 bp = *(const s16x8*)&sPTw[qf & 1][l15][cc];
#pragma unroll
            for (int nt = 0; nt < 4; nt++)
                o[qf][nt] = __builtin_amdgcn_mfma_f32_16x16x32_bf16(
                    av[ks][nt], bp, o[qf][nt], 0, 0, 0);
            lac[qf] = __builtin_amdgcn_mfma_f32_16x16x32_bf16(
                vones, bp, lac[qf], 0, 0, 0);
        }
        __builtin_amdgcn_s_setprio(0);
    }
}

__global__ __launch_bounds__(128, 2) void attn_kernel(
    const unsigned short* __restrict__ Qb,   // [24][4096][64] (pre-scaled)
    const unsigned short* __restrict__ Kb,   // [24][4096][64]
    const unsigned short* __restrict__ Vt,   // [24][64][4096]
    unsigned short* __restrict__ Ob,         // [2][4096][768]
    float* __restrict__ oPart,               // [24][16][2][128][64]
    float* __restrict__ lPart)               // [24][16][2][128]
{
    __shared__ unsigned short sK[2][64][64];     // 16 KB
    __shared__ unsigned short sV[2][64][64];     // 16 KB
    __shared__ unsigned short sPT[2][2][16][64]; // 8 KB  (wave, rotbuf)
    const int bh   = blockIdx.x;
    const int p    = blockIdx.y >> 1;        // pair index 0..15
    const int half = blockIdx.y & 1;
    const int jA = p, jB = 31 - p;
    const int nA = 2 * p + 2;                // k-tiles of q-tile A
    const int aCount = (half == 0) ? nA : 0;
    const int bStart = (half == 0) ? 0 : (31 - 2 * p);
    const int bCount = 33 - aCount;          // half0: 31-2p, half1: 33
    const int tid = threadIdx.x;             // 0..127 (2 waves)
    const int w = tid >> 6, l = tid & 63, g = l >> 4, l15 = l & 15;
    const int wbase = tid & 64;

    const int rl0 = w * 64 + l15;            // local q row (qf0)
    const int b = bh / NHEADS, hd = bh - b * NHEADS;

    s16x8 vones;
#pragma unroll
    for (int e = 0; e < 8; e++) vones[e] = (short)0x3F80;  // bf16 1.0

    const unsigned short* Kbase = Kb + (size_t)bh * TSEQ * DHEAD;
    const unsigned short* Vbase = Vt + (size_t)bh * DHEAD * TSEQ;

    // stage key tile jt into buffer buf (async; swizzle applied global-side)
    // 8 global_load_lds per lane => vmcnt unit is 8.
    auto stage = [&](int jt, int buf) {
        const int kt = jt * 64;
#pragma unroll
        for (int pp = 0; pp < 4; pp++) {
            const int idx = pp * 128 + tid;
            const int row = idx >> 3, pc = idx & 7;
            const int lc = pc ^ (row & 7);
            async_load16(&Kbase[(size_t)(kt + row) * DHEAD + lc * 8],
                         &sK[buf][0][0] + (size_t)(pp * 128 + wbase) * 8);
            async_load16(&Vbase[(size_t)row * TSEQ + kt + lc * 8],
                         &sV[buf][0][0] + (size_t)(pp * 128 + wbase) * 8);
        }
    };

    stage((half == 0) ? 0 : bStart, 0);
    __syncthreads();                          // full drain once (prologue)

    // ================= phase A (half==0 only): q-tile jA, full causal ======
    if (half == 0) {
        const int qg0A = jA * 128 + rl0;
        const unsigned short* QpA = Qb + ((size_t)bh * TSEQ + qg0A) * DHEAD;
        s16x8 qA[4][2];                      // [qf][ks]
#pragma unroll
        for (int qf = 0; qf < 4; qf++) {
            qA[qf][0] = *(const s16x8*)&QpA[(size_t)qf * 16 * DHEAD + g * 8];
            qA[qf][1] = *(const s16x8*)&QpA[(size_t)qf * 16 * DHEAD + 32 + g * 8];
        }

        f32x4 oA[4][4];
        f32x4 lacA[4];
#pragma unroll
        for (int qf = 0; qf < 4; qf++) {
            lacA[qf] = (f32x4){0.f, 0.f, 0.f, 0.f};
#pragma unroll
            for (int nt = 0; nt < 4; nt++)
                oA[qf][nt] = (f32x4){0.f, 0.f, 0.f, 0.f};
        }

        for (int s = 0; s < nA; s++) {
            const int buf = s & 1;
            if (s + 1 < nA) stage(s + 1, buf ^ 1);
            else stage(0, buf ^ 1);          // prefetch phase-B k-tile 0
            asm volatile("s_waitcnt vmcnt(8)" ::: "memory");
            process_tile4(sK[buf], sV[buf], sPT[w], qA, oA, lacA, vones,
                          s * 64, qg0A, s >= nA - 2, g, l15);
            raw_barrier();
        }

        // epilogue A: normalize + write (fully causal tile done)
#pragma unroll
        for (int qf = 0; qf < 4; qf++) {
            const int qg = qg0A + qf * 16;
            const float inv = 1.0f / lacA[qf][0];
#pragma unroll
            for (int nt = 0; nt < 4; nt++) {
                u32x2 pk;
                pk.x = pk2bf(oA[qf][nt][0] * inv, oA[qf][nt][1] * inv);
                pk.y = pk2bf(oA[qf][nt][2] * inv, oA[qf][nt][3] * inv);
                *(u32x2*)&Ob[((size_t)b * TSEQ + qg) * CMODEL + hd * DHEAD +
                             nt * 16 + g * 4] = pk;
            }
        }
    }

    // ================= phase B: q-tile jB, partial k-range =================
    {
        const int qg0B = jB * 128 + rl0;
        const unsigned short* QpB = Qb + ((size_t)bh * TSEQ + qg0B) * DHEAD;
        s16x8 qB[4][2];                      // [qf][ks]
#pragma unroll
        for (int qf = 0; qf < 4; qf++) {
            qB[qf][0] = *(const s16x8*)&QpB[(size_t)qf * 16 * DHEAD + g * 8];
            qB[qf][1] = *(const s16x8*)&QpB[(size_t)qf * 16 * DHEAD + 32 + g * 8];
        }

        f32x4 oB[4][4];
        f32x4 lacB[4];
#pragma unroll
        for (int qf = 0; qf < 4; qf++) {
            lacB[qf] = (f32x4){0.f, 0.f, 0.f, 0.f};
#pragma unroll
            for (int nt = 0; nt < 4; nt++)
                oB[qf][nt] = (f32x4){0.f, 0.f, 0.f, 0.f};
        }

        for (int s = 0; s < bCount; s++) {
            const int buf = (aCount + s) & 1;    // parity continues from A
            if (s + 1 < bCount) {
                stage(bStart + s + 1, buf ^ 1);
                asm volatile("s_waitcnt vmcnt(8)" ::: "memory");
            } else {
                asm volatile("s_waitcnt vmcnt(0)" ::: "memory");
            }
            const bool mask = (half == 1) && (s >= 31);  // diag = last 2 tiles
            process_tile4(sK[buf], sV[buf], sPT[w], qB, oB, lacB, vones,
                          (bStart + s) * 64, qg0B, mask, g, l15);
            raw_barrier();
        }

        // tile B partial: plain stores; combine_kernel adds the halves.
        const int pairIdx = bh * 16 + p;
        const size_t slot = (size_t)pairIdx * 2 + half;
        float* oS = oPart + slot * (128 * 64);
        float* lS = lPart + slot * 128;
#pragma unroll
        for (int qf = 0; qf < 4; qf++) {
            const int rl = rl0 + qf * 16;
#pragma unroll
            for (int nt = 0; nt < 4; nt++)
                *(f32x4*)&oS[(size_t)rl * 64 + nt * 16 + g * 4] = oB[qf][nt];
            if (g == 0) lS[rl] = lacB[qf][0];
        }
    }
}

// --------------------------- partial combine -------------------------------
// o = (oH0 + oH1) / (l0 + l1) for the B q-tiles (jB = 31-p); writes bf16 Ob.
__global__ __launch_bounds__(256) void combine_kernel(
    const float* __restrict__ oPart,         // [24][16][2][128][64]
    const float* __restrict__ lPart,         // [24][16][2][128]
    unsigned short* __restrict__ Ob)         // [2][4096][768]
{
    const int i = blockIdx.x * 256 + threadIdx.x;
    const int c4 = i & 15;
    const int rl = (i >> 4) & 127;
    const int p  = (i >> 11) & 15;
    const int bh = i >> 15;
    const int pair = bh * 16 + p;
    const float* o0 = oPart + ((size_t)pair * 2 + 0) * (128 * 64);
    const float* o1 = oPart + ((size_t)pair * 2 + 1) * (128 * 64);
    const float l0 = lPart[((size_t)pair * 2 + 0) * 128 + rl];
    const float l1 = lPart[((size_t)pair * 2 + 1) * 128 + rl];
    const float inv = 1.0f / (l0 + l1);
    const f32x4 a = *(const f32x4*)&o0[(size_t)rl * 64 + c4 * 4];
    const f32x4 c = *(const f32x4*)&o1[(size_t)rl * 64 + c4 * 4];
    const int b = bh / NHEADS, h = bh - b * NHEADS;
    const int qg = (31 - p) * 128 + rl;
    u32x2 pk;
    pk.x = pk2bf((a[0] + c[0]) * inv, (a[1] + c[1]) * inv);
    pk.y = pk2bf((a[2] + c[2]) * inv, (a[3] + c[3]) * inv);
    *(u32x2*)&Ob[((size_t)b * TSEQ + qg) * CMODEL + h * DHEAD + c4 * 4] = pk;
}

// --------------------------- output projection GEMM (128x128) --------------
// v11 form + XCD swizzle: 384 blocks, 48/XCD = 8 m-panels x 6 n-blocks.
__global__ __launch_bounds__(256) void gemm_out_kernel(
    const unsigned short* __restrict__ A,    // Ob [8192][768] bf16
    const unsigned short* __restrict__ Bw,   // woutb [768][768] bf16
    const float* __restrict__ bias,          // [768]
    float* __restrict__ out)                 // [8192][768] fp32
{
    __shared__ unsigned short sA[128][64];
    __shared__ unsigned short sB[128][64];
    const int idx = blockIdx.x + blockIdx.y * 6;    // hw dispatch order
    const int lid = (idx & 7) * 48 + (idx >> 3);    // bijective (384%8==0)
    const int n0 = (lid % 6) * 128;
    const int m0 = (lid / 6) * 128;
    const int tid = threadIdx.x;
    const int l = tid & 63, g = l >> 4, l15 = l & 15;
    const int w = tid >> 6, wm = w & 1, wn = w >> 1;
    const int wbase = tid & 192;

    f32x4 acc[4][4];
#pragma unroll
    for (int mt = 0; mt < 4; mt++)
#pragma unroll
        for (int nt = 0; nt < 4; nt++) acc[mt][nt] = (f32x4){0.f, 0.f, 0.f, 0.f};

    for (int k0 = 0; k0 < 768; k0 += 64) {
#pragma unroll
        for (int i = 0; i < 4; i++) {
            const int idx2 = i * 256 + tid;
            const int row = idx2 >> 3, pc = idx2 & 7;
            const int lc = pc ^ (row & 7);
            async_load16(&A[(size_t)(m0 + row) * 768 + k0 + lc * 8],
                         &sA[0][0] + (size_t)(i * 256 + wbase) * 8);
            async_load16(&Bw[(size_t)(n0 + row) * 768 + k0 + lc * 8],
                         &sB[0][0] + (size_t)(i * 256 + wbase) * 8);
        }
        __syncthreads();
#pragma unroll
        for (int ks = 0; ks < 2; ks++) {
            const int cc = ((ks * 4 + g) ^ (l15 & 7)) * 8;
            s16x8 af[4], bf[4];
#pragma unroll
            for (int mt = 0; mt < 4; mt++)
                af[mt] = *(const s16x8*)&sA[wm * 64 + mt * 16 + l15][cc];
#pragma unroll
            for (int nt = 0; nt < 4; nt++)
                bf[nt] = *(const s16x8*)&sB[wn * 64 + nt * 16 + l15][cc];
#pragma unroll
            for (int mt = 0; mt < 4; mt++)
#pragma unroll
                for (int nt = 0; nt < 4; nt++)
                    acc[mt][nt] = __builtin_amdgcn_mfma_f32_16x16x32_bf16(
                        af[mt], bf[nt], acc[mt][nt], 0, 0, 0);
        }
        __syncthreads();
    }

#pragma unroll
    for (int nt = 0; nt < 4; nt++) {
        const int n = n0 + wn * 64 + nt * 16 + l15;
        const float bv = bias[n];
#pragma unroll
        for (int mt = 0; mt < 4; mt++)
#pragma unroll
            for (int r = 0; r < 4; r++) {
                const int m = m0 + wm * 64 + mt * 16 + g * 4 + r;
                out[(size_t)m * CMODEL + n] = acc[mt][nt][r] + bv;
            }
    }
}

// --------------------------- launch ----------------------------------------
extern "C" void kernel_launch(void* const* d_in, const int* in_sizes, int n_in,
                              void* d_out, int out_size, void* d_ws, size_t ws_size,
                              hipStream_t stream) {
    const float* x     = (const float*)d_in[0];
    const float* w_qkv = (const float*)d_in[1];
    const float* b_qkv = (const float*)d_in[2];
    const float* w_out = (const float*)d_in[3];
    const float* b_out = (const float*)d_in[4];
    float* out = (float*)d_out;

    char* ws = (char*)d_ws;
    size_t off = 0;
    auto alloc = [&](size_t bytes) -> void* {
        void* p = (void*)(ws + off);
        off += (bytes + 255) & ~(size_t)255;
        return p;
    };
    unsigned short* xb    = (unsigned short*)alloc((size_t)MTOT * CMODEL * 2);
    unsigned short* wqkvb = (unsigned short*)alloc((size_t)NQKV * CMODEL * 2);
    unsigned short* woutb = (unsigned short*)alloc((size_t)CMODEL * CMODEL * 2);
    unsigned short* Qb    = (unsigned short*)alloc((size_t)NBH * TSEQ * DHEAD * 2);
    unsigned short* Kb    = (unsigned short*)alloc((size_t)NBH * TSEQ * DHEAD * 2);
    unsigned short* Vt    = (unsigned short*)alloc((size_t)NBH * TSEQ * DHEAD * 2);
    unsigned short* Ob    = (unsigned short*)alloc((size_t)MTOT * CMODEL * 2);
    float* oPart = (float*)alloc((size_t)NBH * 16 * 2 * 128 * 64 * 4);
    float* lPart = (float*)alloc((size_t)NBH * 16 * 2 * 128 * 4);

    const int n40 = MTOT * CMODEL / 4;       // 1572864
    const int n41 = NQKV * CMODEL / 4;       // 442368
    const int n42 = CMODEL * CMODEL / 4;     // 147456
    const int nblk = (n40 + n41 + n42 + 255) / 256;
    cvt3_kernel<<<dim3(nblk), 256, 0, stream>>>(
        x, w_qkv, w_out, xb, wqkvb, woutb, n40, n41, n42);

    gemm_qkv_kernel<<<dim3(NQKV / 128, MTOT / 128), 256, 0, stream>>>(
        xb, wqkvb, b_qkv, Qb, Kb, Vt);
    attn_kernel<<<dim3(NBH, 32), 128, 0, stream>>>(
        Qb, Kb, Vt, Ob, oPart, lPart);
    combine_kernel<<<dim3(NBH * 16 * 128 * 16 / 256), 256, 0, stream>>>(
        oPart, lPart, Ob);
    gemm_out_kernel<<<dim3(CMODEL / 128, MTOT / 128), 256, 0, stream>>>(
        Ob, woutb, b_out, out);
}

// Round 9
// 225.415 us; speedup vs baseline: 1.1068x; 1.1068x over previous
//
#include <hip/hip_runtime.h>

// ---------------------------------------------------------------------------
// MultiHeadCausalAttention: B=2, T=4096, C=768, H=12, Dh=64
// v15: consolidation round.
//  (1) attn: exact revert to v13 (75.5us measured). v14's 2-wave reuse-4
//      halved waves/CU (12->6); kernel is LATENCY-bound (no pipe >52%), so
//      occupancy loss dominated the LDS-traffic saving (96us, Occ 13%).
//      Rule: this structure needs >=12 waves/CU.
//  (2) gemm_out: 128x96 tile -> 512 blocks = exactly 2/CU (was 384 = 1.5/CU,
//      half the CUs ran 2 serial blocks). Makespan 24->18 k-step-units.
//      Epilogue is plain out[m*768+n] (no head alignment) so the 96-wide
//      reindex is safe; gemm_qkv keeps its head-aligned 128 tile.
// ---------------------------------------------------------------------------

#define NHEADS 12
#define DHEAD  64
#define TSEQ   4096
#define BATCH  2
#define CMODEL 768
#define MTOT   (BATCH * TSEQ)   /* 8192 */
#define NQKV   (3 * CMODEL)     /* 2304 */
#define NBH    (BATCH * NHEADS) /* 24 */

typedef __attribute__((ext_vector_type(8))) short s16x8;
typedef __attribute__((ext_vector_type(4))) float f32x4;
typedef __attribute__((ext_vector_type(4))) unsigned short u16x4;
typedef __attribute__((ext_vector_type(2))) unsigned int u32x2;

__device__ __forceinline__ unsigned short f2bf(float f) {
    unsigned u = __builtin_bit_cast(unsigned, f);
    u += 0x7fffu + ((u >> 16) & 1u);   // round-to-nearest-even
    return (unsigned short)(u >> 16);
}

__device__ __forceinline__ unsigned pk2bf(float a, float b) {
    return (unsigned)f2bf(a) | ((unsigned)f2bf(b) << 16);
}

// packed f32x2 -> bf16x2 in one VOP3 (no builtin on gfx950; RTNE; S0->lo)
__device__ __forceinline__ unsigned cvtpk(float lo, float hi) {
    unsigned r;
    asm("v_cvt_pk_bf16_f32 %0, %1, %2" : "=v"(r) : "v"(lo), "v"(hi));
    return r;
}

__device__ __forceinline__ float fexp2(float x) {
    return __builtin_amdgcn_exp2f(x);
}

// async global -> LDS, 16B per lane; lds dest = wave-uniform base + lane*16.
__device__ __forceinline__ void async_load16(const void* g, void* l) {
    __builtin_amdgcn_global_load_lds(
        (const __attribute__((address_space(1))) unsigned*)g,
        (__attribute__((address_space(3))) unsigned*)l, 16, 0, 0);
}

// raw workgroup barrier with backend-scheduler pinning (no vmcnt drain)
__device__ __forceinline__ void raw_barrier() {
    __builtin_amdgcn_sched_barrier(0);
    __builtin_amdgcn_s_barrier();
    __builtin_amdgcn_sched_barrier(0);
}

// --------------------------- fp32 -> bf16 cvt (3 tensors, 1 launch) --------
__global__ __launch_bounds__(256) void cvt3_kernel(
    const float* __restrict__ s0, const float* __restrict__ s1,
    const float* __restrict__ s2,
    unsigned short* __restrict__ d0, unsigned short* __restrict__ d1,
    unsigned short* __restrict__ d2, int n0, int n1, int n2)
{
    int i = blockIdx.x * 256 + threadIdx.x;
    const float* s; unsigned short* d; int j;
    if (i < n0)                { s = s0; d = d0; j = i; }
    else if (i < n0 + n1)      { s = s1; d = d1; j = i - n0; }
    else if (i < n0 + n1 + n2) { s = s2; d = d2; j = i - n0 - n1; }
    else return;
    f32x4 v = ((const f32x4*)s)[j];
    u32x2 o;
    o.x = pk2bf(v.x, v.y);
    o.y = pk2bf(v.z, v.w);
    ((u32x2*)d)[j] = o;
}

// --------------------------- QKV projection GEMM (128x128) -----------------
// XCD-chunked swizzle: 1152 blocks, 144/XCD = 8 m-panels x 18 n-blocks.
__global__ __launch_bounds__(256) void gemm_qkv_kernel(
    const unsigned short* __restrict__ A,    // [8192][768] bf16 (x)
    const unsigned short* __restrict__ Bw,   // [2304][768] bf16 (w_qkv)
    const float* __restrict__ bias,          // [2304]
    unsigned short* __restrict__ Qb,
    unsigned short* __restrict__ Kb,
    unsigned short* __restrict__ Vt)
{
    __shared__ unsigned short sA[128][64];
    __shared__ unsigned short sB[128][64];
    const int idx = blockIdx.x + blockIdx.y * 18;   // hw dispatch order
    const int lid = (idx & 7) * 144 + (idx >> 3);   // bijective (1152%8==0)
    const int n0 = (lid % 18) * 128;
    const int m0 = (lid / 18) * 128;
    const int tid = threadIdx.x;
    const int l = tid & 63, g = l >> 4, l15 = l & 15;
    const int w = tid >> 6, wm = w & 1, wn = w >> 1;
    const int wbase = tid & 192;
    const int seg = n0 / 768;                // 0=Q 1=K 2=V (block-uniform)

    f32x4 acc[4][4];
#pragma unroll
    for (int a = 0; a < 4; a++)
#pragma unroll
        for (int b = 0; b < 4; b++) acc[a][b] = (f32x4){0.f, 0.f, 0.f, 0.f};

    if (seg < 2) {
        // ---- Q/K path: acc[nt][mt] = C^T tile (rows = n, cols = m) ----
        for (int k0 = 0; k0 < 768; k0 += 64) {
#pragma unroll
            for (int i = 0; i < 4; i++) {
                const int idx2 = i * 256 + tid;
                const int row = idx2 >> 3, pc = idx2 & 7;
                const int lc = pc ^ (row & 7);
                async_load16(&A[(size_t)(m0 + row) * 768 + k0 + lc * 8],
                             &sA[0][0] + (size_t)(i * 256 + wbase) * 8);
                async_load16(&Bw[(size_t)(n0 + row) * 768 + k0 + lc * 8],
                             &sB[0][0] + (size_t)(i * 256 + wbase) * 8);
            }
            __syncthreads();
#pragma unroll
            for (int ks = 0; ks < 2; ks++) {
                const int cc = ((ks * 4 + g) ^ (l15 & 7)) * 8;
                s16x8 af[4], bf[4];
#pragma unroll
                for (int mt = 0; mt < 4; mt++)
                    af[mt] = *(const s16x8*)&sA[wm * 64 + mt * 16 + l15][cc];
#pragma unroll
                for (int nt = 0; nt < 4; nt++)
                    bf[nt] = *(const s16x8*)&sB[wn * 64 + nt * 16 + l15][cc];
#pragma unroll
                for (int nt = 0; nt < 4; nt++)
#pragma unroll
                    for (int mt = 0; mt < 4; mt++)
                        acc[nt][mt] = __builtin_amdgcn_mfma_f32_16x16x32_bf16(
                            bf[nt], af[mt], acc[nt][mt], 0, 0, 0);
            }
            __syncthreads();
        }

        unsigned short* dst = (seg == 0) ? Qb : Kb;
        const float sc = (seg == 0) ? 0.18033688011f : 1.0f;  // 0.125*log2e
        const int hh = ((n0 - seg * 768) + wn * 64) >> 6;     // uniform head
#pragma unroll
        for (int nt = 0; nt < 4; nt++) {
            const int dh = nt * 16 + g * 4;                    // + r
            const f32x4 bv4 = *(const f32x4*)&bias[n0 + wn * 64 + dh];
#pragma unroll
            for (int mt = 0; mt < 4; mt++) {
                const int m = m0 + wm * 64 + mt * 16 + l15;
                const int b = m >> 12, t = m & 4095;
                u32x2 pk;
                pk.x = pk2bf((acc[nt][mt][0] + bv4[0]) * sc,
                             (acc[nt][mt][1] + bv4[1]) * sc);
                pk.y = pk2bf((acc[nt][mt][2] + bv4[2]) * sc,
                             (acc[nt][mt][3] + bv4[3]) * sc);
                *(u32x2*)&dst[(((size_t)(b * NHEADS + hh) * TSEQ + t) << 6) + dh] = pk;
            }
        }
    } else {
        // ---- V path: acc[mt][nt] = C tile (rows = m), store transposed ----
        for (int k0 = 0; k0 < 768; k0 += 64) {
#pragma unroll
            for (int i = 0; i < 4; i++) {
                const int idx2 = i * 256 + tid;
                const int row = idx2 >> 3, pc = idx2 & 7;
                const int lc = pc ^ (row & 7);
                async_load16(&A[(size_t)(m0 + row) * 768 + k0 + lc * 8],
                             &sA[0][0] + (size_t)(i * 256 + wbase) * 8);
                async_load16(&Bw[(size_t)(n0 + row) * 768 + k0 + lc * 8],
                             &sB[0][0] + (size_t)(i * 256 + wbase) * 8);
            }
            __syncthreads();
#pragma unroll
            for (int ks = 0; ks < 2; ks++) {
                const int cc = ((ks * 4 + g) ^ (l15 & 7)) * 8;
                s16x8 af[4], bf[4];
#pragma unroll
                for (int mt = 0; mt < 4; mt++)
                    af[mt] = *(const s16x8*)&sA[wm * 64 + mt * 16 + l15][cc];
#pragma unroll
                for (int nt = 0; nt < 4; nt++)
                    bf[nt] = *(const s16x8*)&sB[wn * 64 + nt * 16 + l15][cc];
#pragma unroll
                for (int mt = 0; mt < 4; mt++)
#pragma unroll
                    for (int nt = 0; nt < 4; nt++)
                        acc[mt][nt] = __builtin_amdgcn_mfma_f32_16x16x32_bf16(
                            af[mt], bf[nt], acc[mt][nt], 0, 0, 0);
            }
            __syncthreads();
        }

#pragma unroll
        for (int nt = 0; nt < 4; nt++) {
            const int n = n0 + wn * 64 + nt * 16 + l15;
            const float bv = bias[n];
            const int hh = (n - 1536) >> 6;
            const int dh = n & 63;
#pragma unroll
            for (int mt = 0; mt < 4; mt++) {
                const int mg = m0 + wm * 64 + mt * 16 + g * 4;
                const int b = mg >> 12, t = mg & 4095;
                u32x2 pk;
                pk.x = pk2bf(acc[mt][nt][0] + bv, acc[mt][nt][1] + bv);
                pk.y = pk2bf(acc[mt][nt][2] + bv, acc[mt][nt][3] + bv);
                *(u32x2*)&Vt[((size_t)(b * NHEADS + hh) * DHEAD + dh) * TSEQ + t] = pk;
            }
        }
    }
}

// --------------------------- flash attention (v13 form) --------------------
// Per-iteration body. Exactly one call site per loop so arrays stay
// SROA-promoted (no address-taken scratch).
__device__ __forceinline__ void process_tile(
    const unsigned short (&sKb)[64][64],
    const unsigned short (&sVb)[64][64],
    unsigned short (&sPTw)[2][16][64],
    const s16x8 (&qa)[2][2],            // [qf][ks]
    f32x4 (&o)[2][4], f32x4 (&lac)[2],
    s16x8 vones, int kt, int qg0, bool mask, int g, int l15)
{
    const int xk = l15 & 7;
    const int qg1 = qg0 + 16;

    // ---- QK^T for both q-frags (K frags read once, used twice) ----
    f32x4 st[2][4];
#pragma unroll
    for (int nt = 0; nt < 4; nt++) {
        st[0][nt] = (f32x4){0.f, 0.f, 0.f, 0.f};
        st[1][nt] = (f32x4){0.f, 0.f, 0.f, 0.f};
    }
    __builtin_amdgcn_s_setprio(1);
#pragma unroll
    for (int ks = 0; ks < 2; ks++) {
        const int cc = ((ks * 4 + g) ^ xk) * 8;
#pragma unroll
        for (int nt = 0; nt < 4; nt++) {
            const s16x8 akf = *(const s16x8*)&sKb[nt * 16 + l15][cc];
            st[0][nt] = __builtin_amdgcn_mfma_f32_16x16x32_bf16(
                akf, qa[0][ks], st[0][nt], 0, 0, 0);
            st[1][nt] = __builtin_amdgcn_mfma_f32_16x16x32_bf16(
                akf, qa[1][ks], st[1][nt], 0, 0, 0);
        }
    }
    __builtin_amdgcn_s_setprio(0);

    // ---- causal mask (block-uniform predicate) ----
    if (mask) {
#pragma unroll
        for (int nt = 0; nt < 4; nt++)
#pragma unroll
            for (int r = 0; r < 4; r++) {
                const int key = kt + nt * 16 + g * 4 + r;
                if (key > qg0) st[0][nt][r] = -1e30f;
                if (key > qg1) st[1][nt][r] = -1e30f;
            }
    }

    // ---- softmax numerator + pack to sPT (wave-private, no barrier) ----
#pragma unroll
    for (int qf = 0; qf < 2; qf++) {
#pragma unroll
        for (int nt = 0; nt < 4; nt++) {
            float p0 = fexp2(st[qf][nt][0]);
            float p1 = fexp2(st[qf][nt][1]);
            float p2 = fexp2(st[qf][nt][2]);
            float p3 = fexp2(st[qf][nt][3]);
            u32x2 pk;
            pk.x = cvtpk(p0, p1);
            pk.y = cvtpk(p2, p3);
            const int phys = ((nt * 2 + (g >> 1)) ^ xk) * 8 + (g & 1) * 4;
            *(u32x2*)&sPTw[qf][l15][phys] = pk;
        }
    }

    // ---- PV (V frags read once, used twice) + l via ones-row MFMA ----
    __builtin_amdgcn_s_setprio(1);
#pragma unroll
    for (int ks = 0; ks < 2; ks++) {
        const int cc = ((ks * 4 + g) ^ xk) * 8;
        const s16x8 bp0 = *(const s16x8*)&sPTw[0][l15][cc];
        const s16x8 bp1 = *(const s16x8*)&sPTw[1][l15][cc];
#pragma unroll
        for (int nt = 0; nt < 4; nt++) {
            const s16x8 avf = *(const s16x8*)&sVb[nt * 16 + l15][cc];
            o[0][nt] = __builtin_amdgcn_mfma_f32_16x16x32_bf16(
                avf, bp0, o[0][nt], 0, 0, 0);
            o[1][nt] = __builtin_amdgcn_mfma_f32_16x16x32_bf16(
                avf, bp1, o[1][nt], 0, 0, 0);
        }
        lac[0] = __builtin_amdgcn_mfma_f32_16x16x32_bf16(vones, bp0, lac[0], 0, 0, 0);
        lac[1] = __builtin_amdgcn_mfma_f32_16x16x32_bf16(vones, bp1, lac[1], 0, 0, 0);
    }
    __builtin_amdgcn_s_setprio(0);
}

__global__ __launch_bounds__(256, 3) void attn_kernel(
    const unsigned short* __restrict__ Qb,   // [24][4096][64] (pre-scaled)
    const unsigned short* __restrict__ Kb,   // [24][4096][64]
    const unsigned short* __restrict__ Vt,   // [24][64][4096]
    unsigned short* __restrict__ Ob,         // [2][4096][768]
    float* __restrict__ oPart,               // [24][16][2][128][64]
    float* __restrict__ lPart)               // [24][16][2][128]
{
    __shared__ unsigned short sK[2][64][64];
    __shared__ unsigned short sV[2][64][64];
    __shared__ unsigned short sPT[4][2][16][64];
    const int bh   = blockIdx.x;
    const int p    = blockIdx.y >> 1;        // pair index 0..15
    const int half = blockIdx.y & 1;
    const int jA = p, jB = 31 - p;
    const int nA = 2 * p + 2;                // k-tiles of q-tile A
    const int aCount = (half == 0) ? nA : 0;
    const int bStart = (half == 0) ? 0 : (31 - 2 * p);
    const int bCount = 33 - aCount;          // half0: 31-2p, half1: 33
    const int tid = threadIdx.x;
    const int w = tid >> 6, l = tid & 63, g = l >> 4, l15 = l & 15;
    const int wbase = tid & 192;

    const int rl0 = w * 32 + l15;            // local q row (qf0)
    const int b = bh / NHEADS, hd = bh - b * NHEADS;

    s16x8 vones;
#pragma unroll
    for (int e = 0; e < 8; e++) vones[e] = (short)0x3F80;  // bf16 1.0

    const unsigned short* Kbase = Kb + (size_t)bh * TSEQ * DHEAD;
    const unsigned short* Vbase = Vt + (size_t)bh * DHEAD * TSEQ;

    // stage key tile jt into buffer buf (async; swizzle applied global-side)
    // 4 global_load_lds instructions per lane => vmcnt unit is 4.
    auto stage = [&](int jt, int buf) {
        const int kt = jt * 64;
#pragma unroll
        for (int pp = 0; pp < 2; pp++) {
            const int idx = pp * 256 + tid;
            const int row = idx >> 3, pc = idx & 7;
            const int lc = pc ^ (row & 7);
            async_load16(&Kbase[(size_t)(kt + row) * DHEAD + lc * 8],
                         &sK[buf][0][0] + (size_t)(pp * 256 + wbase) * 8);
            async_load16(&Vbase[(size_t)row * TSEQ + kt + lc * 8],
                         &sV[buf][0][0] + (size_t)(pp * 256 + wbase) * 8);
        }
    };

    stage((half == 0) ? 0 : bStart, 0);
    __syncthreads();                          // full drain once (prologue)

    // ================= phase A (half==0 only): q-tile jA, full causal ======
    if (half == 0) {
        const int qg0A = jA * 128 + rl0;
        const unsigned short* QpA = Qb + ((size_t)bh * TSEQ + qg0A) * DHEAD;
        s16x8 qA[2][2];                      // [qf][ks]
        qA[0][0] = *(const s16x8*)&QpA[g * 8];
        qA[0][1] = *(const s16x8*)&QpA[32 + g * 8];
        qA[1][0] = *(const s16x8*)&QpA[16 * DHEAD + g * 8];
        qA[1][1] = *(const s16x8*)&QpA[16 * DHEAD + 32 + g * 8];

        f32x4 oA[2][4];
        f32x4 lacA[2];
#pragma unroll
        for (int nt = 0; nt < 4; nt++) {
            oA[0][nt] = (f32x4){0.f, 0.f, 0.f, 0.f};
            oA[1][nt] = (f32x4){0.f, 0.f, 0.f, 0.f};
        }
        lacA[0] = (f32x4){0.f, 0.f, 0.f, 0.f};
        lacA[1] = (f32x4){0.f, 0.f, 0.f, 0.f};

        for (int s = 0; s < nA; s++) {
            const int buf = s & 1;
            if (s + 1 < nA) stage(s + 1, buf ^ 1);
            else stage(0, buf ^ 1);          // prefetch phase-B k-tile 0
            asm volatile("s_waitcnt vmcnt(4)" ::: "memory");
            process_tile(sK[buf], sV[buf], sPT[w], qA, oA, lacA, vones,
                         s * 64, qg0A, s >= nA - 2, g, l15);
            raw_barrier();
        }

        // epilogue A: normalize + write (fully causal tile done)
#pragma unroll
        for (int qf = 0; qf < 2; qf++) {
            const int qg = qg0A + qf * 16;
            const float inv = 1.0f / lacA[qf][0];
#pragma unroll
            for (int nt = 0; nt < 4; nt++) {
                u32x2 pk;
                pk.x = pk2bf(oA[qf][nt][0] * inv, oA[qf][nt][1] * inv);
                pk.y = pk2bf(oA[qf][nt][2] * inv, oA[qf][nt][3] * inv);
                *(u32x2*)&Ob[((size_t)b * TSEQ + qg) * CMODEL + hd * DHEAD +
                             nt * 16 + g * 4] = pk;
            }
        }
    }

    // ================= phase B: q-tile jB, partial k-range =================
    {
        const int qg0B = jB * 128 + rl0;
        const unsigned short* QpB = Qb + ((size_t)bh * TSEQ + qg0B) * DHEAD;
        s16x8 qB[2][2];                      // [qf][ks]
        qB[0][0] = *(const s16x8*)&QpB[g * 8];
        qB[0][1] = *(const s16x8*)&QpB[32 + g * 8];
        qB[1][0] = *(const s16x8*)&QpB[16 * DHEAD + g * 8];
        qB[1][1] = *(const s16x8*)&QpB[16 * DHEAD + 32 + g * 8];

        f32x4 oB[2][4];
        f32x4 lacB[2];
#pragma unroll
        for (int nt = 0; nt < 4; nt++) {
            oB[0][nt] = (f32x4){0.f, 0.f, 0.f, 0.f};
            oB[1][nt] = (f32x4){0.f, 0.f, 0.f, 0.f};
        }
        lacB[0] = (f32x4){0.f, 0.f, 0.f, 0.f};
        lacB[1] = (f32x4){0.f, 0.f, 0.f, 0.f};

        for (int s = 0; s < bCount; s++) {
            const int buf = (aCount + s) & 1;    // parity continues from A
            if (s + 1 < bCount) {
                stage(bStart + s + 1, buf ^ 1);
                asm volatile("s_waitcnt vmcnt(4)" ::: "memory");
            } else {
                asm volatile("s_waitcnt vmcnt(0)" ::: "memory");
            }
            const bool mask = (half == 1) && (s >= 31);  // diag = last 2 tiles
            process_tile(sK[buf], sV[buf], sPT[w], qB, oB, lacB, vones,
                         (bStart + s) * 64, qg0B, mask, g, l15);
            raw_barrier();
        }

        // tile B partial: plain stores; combine_kernel adds the halves.
        const int pairIdx = bh * 16 + p;
        const size_t slot = (size_t)pairIdx * 2 + half;
        float* oS = oPart + slot * (128 * 64);
        float* lS = lPart + slot * 128;
#pragma unroll
        for (int qf = 0; qf < 2; qf++) {
            const int rl = rl0 + qf * 16;
#pragma unroll
            for (int nt = 0; nt < 4; nt++)
                *(f32x4*)&oS[(size_t)rl * 64 + nt * 16 + g * 4] = oB[qf][nt];
            if (g == 0) lS[rl] = lacB[qf][0];
        }
    }
}

// --------------------------- partial combine -------------------------------
// o = (oH0 + oH1) / (l0 + l1) for the B q-tiles (jB = 31-p); writes bf16 Ob.
__global__ __launch_bounds__(256) void combine_kernel(
    const float* __restrict__ oPart,         // [24][16][2][128][64]
    const float* __restrict__ lPart,         // [24][16][2][128]
    unsigned short* __restrict__ Ob)         // [2][4096][768]
{
    const int i = blockIdx.x * 256 + threadIdx.x;
    const int c4 = i & 15;
    const int rl = (i >> 4) & 127;
    const int p  = (i >> 11) & 15;
    const int bh = i >> 15;
    const int pair = bh * 16 + p;
    const float* o0 = oPart + ((size_t)pair * 2 + 0) * (128 * 64);
    const float* o1 = oPart + ((size_t)pair * 2 + 1) * (128 * 64);
    const float l0 = lPart[((size_t)pair * 2 + 0) * 128 + rl];
    const float l1 = lPart[((size_t)pair * 2 + 1) * 128 + rl];
    const float inv = 1.0f / (l0 + l1);
    const f32x4 a = *(const f32x4*)&o0[(size_t)rl * 64 + c4 * 4];
    const f32x4 c = *(const f32x4*)&o1[(size_t)rl * 64 + c4 * 4];
    const int b = bh / NHEADS, h = bh - b * NHEADS;
    const int qg = (31 - p) * 128 + rl;
    u32x2 pk;
    pk.x = pk2bf((a[0] + c[0]) * inv, (a[1] + c[1]) * inv);
    pk.y = pk2bf((a[2] + c[2]) * inv, (a[3] + c[3]) * inv);
    *(u32x2*)&Ob[((size_t)b * TSEQ + qg) * CMODEL + h * DHEAD + c4 * 4] = pk;
}

// --------------------------- output projection GEMM (128x96) ---------------
// 512 blocks = exactly 2/CU (was 384 = 1.5/CU: half the CUs ran 2 serial
// blocks). XCD swizzle: 512%8==0, 64/XCD = 8 m-panels x 8 n-blocks
// (A 1.5MB + B 1.1MB L2-resident). Epilogue is plain out[m*768+n], so the
// 96-wide (48/wave, nt=3) reindex has no head-alignment hazard.
__global__ __launch_bounds__(256) void gemm_out_kernel(
    const unsigned short* __restrict__ A,    // Ob [8192][768] bf16
    const unsigned short* __restrict__ Bw,   // woutb [768][768] bf16
    const float* __restrict__ bias,          // [768]
    float* __restrict__ out)                 // [8192][768] fp32
{
    __shared__ unsigned short sA[128][64];
    __shared__ unsigned short sB[96][64];
    const int idx = blockIdx.x;                     // hw dispatch order
    const int lid = (idx & 7) * 64 + (idx >> 3);    // bijective (512%8==0)
    const int n0 = (lid % 8) * 96;
    const int m0 = (lid / 8) * 128;
    const int tid = threadIdx.x;
    const int l = tid & 63, g = l >> 4, l15 = l & 15;
    const int w = tid >> 6, wm = w & 1, wn = w >> 1;
    const int wbase = tid & 192;

    f32x4 acc[4][3];
#pragma unroll
    for (int mt = 0; mt < 4; mt++)
#pragma unroll
        for (int nt = 0; nt < 3; nt++) acc[mt][nt] = (f32x4){0.f, 0.f, 0.f, 0.f};

    for (int k0 = 0; k0 < 768; k0 += 64) {
#pragma unroll
        for (int i = 0; i < 4; i++) {                 // A: 128 rows x 8 slots
            const int idx2 = i * 256 + tid;
            const int row = idx2 >> 3, pc = idx2 & 7;
            const int lc = pc ^ (row & 7);
            async_load16(&A[(size_t)(m0 + row) * 768 + k0 + lc * 8],
                         &sA[0][0] + (size_t)(i * 256 + wbase) * 8);
        }
#pragma unroll
        for (int i = 0; i < 3; i++) {                 // B: 96 rows x 8 slots
            const int idx2 = i * 256 + tid;
            const int row = idx2 >> 3, pc = idx2 & 7;
            const int lc = pc ^ (row & 7);
            async_load16(&Bw[(size_t)(n0 + row) * 768 + k0 + lc * 8],
                         &sB[0][0] + (size_t)(i * 256 + wbase) * 8);
        }
        __syncthreads();
#pragma unroll
        for (int ks = 0; ks < 2; ks++) {
            const int cc = ((ks * 4 + g) ^ (l15 & 7)) * 8;
            s16x8 af[4], bf[3];
#pragma unroll
            for (int mt = 0; mt < 4; mt++)
                af[mt] = *(const s16x8*)&sA[wm * 64 + mt * 16 + l15][cc];
#pragma unroll
            for (int nt = 0; nt < 3; nt++)
                bf[nt] = *(const s16x8*)&sB[wn * 48 + nt * 16 + l15][cc];
#pragma unroll
            for (int mt = 0; mt < 4; mt++)
#pragma unroll
                for (int nt = 0; nt < 3; nt++)
                    acc[mt][nt] = __builtin_amdgcn_mfma_f32_16x16x32_bf16(
                        af[mt], bf[nt], acc[mt][nt], 0, 0, 0);
        }
        __syncthreads();
    }

#pragma unroll
    for (int nt = 0; nt < 3; nt++) {
        const int n = n0 + wn * 48 + nt * 16 + l15;
        const float bv = bias[n];
#pragma unroll
        for (int mt = 0; mt < 4; mt++)
#pragma unroll
            for (int r = 0; r < 4; r++) {
                const int m = m0 + wm * 64 + mt * 16 + g * 4 + r;
                out[(size_t)m * CMODEL + n] = acc[mt][nt][r] + bv;
            }
    }
}

// --------------------------- launch ----------------------------------------
extern "C" void kernel_launch(void* const* d_in, const int* in_sizes, int n_in,
                              void* d_out, int out_size, void* d_ws, size_t ws_size,
                              hipStream_t stream) {
    const float* x     = (const float*)d_in[0];
    const float* w_qkv = (const float*)d_in[1];
    const float* b_qkv = (const float*)d_in[2];
    const float* w_out = (const float*)d_in[3];
    const float* b_out = (const float*)d_in[4];
    float* out = (float*)d_out;

    char* ws = (char*)d_ws;
    size_t off = 0;
    auto alloc = [&](size_t bytes) -> void* {
        void* p = (void*)(ws + off);
        off += (bytes + 255) & ~(size_t)255;
        return p;
    };
    unsigned short* xb    = (unsigned short*)alloc((size_t)MTOT * CMODEL * 2);
    unsigned short* wqkvb = (unsigned short*)alloc((size_t)NQKV * CMODEL * 2);
    unsigned short* woutb = (unsigned short*)alloc((size_t)CMODEL * CMODEL * 2);
    unsigned short* Qb    = (unsigned short*)alloc((size_t)NBH * TSEQ * DHEAD * 2);
    unsigned short* Kb    = (unsigned short*)alloc((size_t)NBH * TSEQ * DHEAD * 2);
    unsigned short* Vt    = (unsigned short*)alloc((size_t)NBH * TSEQ * DHEAD * 2);
    unsigned short* Ob    = (unsigned short*)alloc((size_t)MTOT * CMODEL * 2);
    float* oPart = (float*)alloc((size_t)NBH * 16 * 2 * 128 * 64 * 4);
    float* lPart = (float*)alloc((size_t)NBH * 16 * 2 * 128 * 4);

    const int n40 = MTOT * CMODEL / 4;       // 1572864
    const int n41 = NQKV * CMODEL / 4;       // 442368
    const int n42 = CMODEL * CMODEL / 4;     // 147456
    const int nblk = (n40 + n41 + n42 + 255) / 256;
    cvt3_kernel<<<dim3(nblk), 256, 0, stream>>>(
        x, w_qkv, w_out, xb, wqkvb, woutb, n40, n41, n42);

    gemm_qkv_kernel<<<dim3(NQKV / 128, MTOT / 128), 256, 0, stream>>>(
        xb, wqkvb, b_qkv, Qb, Kb, Vt);
    attn_kernel<<<dim3(NBH, 32), 256, 0, stream>>>(
        Qb, Kb, Vt, Ob, oPart, lPart);
    combine_kernel<<<dim3(NBH * 16 * 128 * 16 / 256), 256, 0, stream>>>(
        oPart, lPart, Ob);
    gemm_out_kernel<<<dim3(512), 256, 0, stream>>>(
        Ob, woutb, b_out, out);
}